// Round 6
// baseline (744.151 us; speedup 1.0000x reference)
//
#include <hip/hip_runtime.h>
#include <hip/hip_bf16.h>
#include <hip/hip_cooperative_groups.h>

namespace cg = cooperative_groups;

// GCN 2-layer: h1 = relu(Ahat @ (x@W1) + b1); out = Ahat @ (h1@W2) + b2
// Ahat = D^-1/2 (A + I) D^-1/2.
//
// R13: SINGLE COOPERATIVE KERNEL. Evidence the pipeline is dispatch-gap
// bound, not kernel bound: R3 added 2 dispatches -> +37 us (+18.5/dispatch,
// >> the ~5 us of duplicated work); bottom-up roofline of all 9 kernels sums
// to ~105-130 us vs 215 measured -> ~90 us unexplained ~= 9 x ~10 us launch
// gap. Fuse everything; 8 grid.sync()s replace 8 gaps. Phase bodies are the
// PROVEN R1 code verbatim.
// R14 (hardening after infra-flake round): (a) occupancy PRE-CHECK picks
// coop vs classic before any launch (a failing coop launch could invalidate
// stream capture); (b) grid sized to guaranteed co-residency and ALL phases
// loop over virtual blocks -> no deadlock if assumed != actual occupancy;
// (c) hist_body trailing barrier for LDS reuse across vb loop.
// R11: agg is NOT gather-instr bound (R1 A/B) and NOT L3-capacity bound
// (R3 A/B); its floor is per-lane L1-miss/L2-request throughput.
// R3: never funnel E atomics into few global addresses.
// R9: sentinel padding kills live-mask VALU. R8: full-width batches.
// R5: 64-wide scan in wave 0 uses shfl.

#define NB_MAX 1024
#define NVB    1024   // virtual block count for hist/scatter chunking

struct GcnP {
    const float* x; const int* ei; const float* W1; const float* b1;
    const float* W2; const float* b2;
    int n, E, nb, chunk;
    int* histT; int* total; int* base; unsigned* packed;
    unsigned short* ssrcp; int* qbeg; int* qcnt; float* dinv;
    unsigned short* hs1; float* hB; unsigned short* hs2; float* out;
};

__device__ inline unsigned short f2bf(float f) {      // RNE fp32 -> bf16
    unsigned u = __builtin_bit_cast(unsigned, f);
    return (unsigned short)((u + 0x7FFFu + ((u >> 16) & 1u)) >> 16);
}
__device__ inline float blo(unsigned u) {
    return __builtin_bit_cast(float, u << 16);
}
__device__ inline float bhi(unsigned u) {
    return __builtin_bit_cast(float, u & 0xFFFF0000u);
}

// ---- phase: per-virtual-block bucket histogram ----------------------------

__device__ inline void hist_body(const int* __restrict__ ei, int E, int nb,
                                 int chunk, int* __restrict__ histT, int vb,
                                 int* h) {
    const int t = threadIdx.x;
    for (int i = t; i < nb; i += 256) h[i] = 0;
    __syncthreads();
    int e0 = vb * chunk, e1 = min(E, e0 + chunk);
    for (int e = e0 + t; e < e1; e += 256)
        atomicAdd(&h[ei[E + e] >> 6], 1);              // LDS atomic
    __syncthreads();
    for (int b = t; b < nb; b += 256)
        histT[(size_t)b * NVB + vb] = h[b];            // [bucket][vblock]
    __syncthreads();                                   // h reuse safety
}

// ---- phase: 256-thread scan of m<=1024 ints (4/thread) --------------------
// exclusive in dst (may alias src); grand total -> *grand_out and/or dst[m].

__device__ inline void scan_block(const int* __restrict__ src,
                                  int* __restrict__ dst, int m,
                                  int* grand_out, bool write_end, int* sm) {
    const int t = threadIdx.x;
    const int idx = t * 4;
    int a[4]; int s = 0;
#pragma unroll
    for (int i = 0; i < 4; ++i) {
        a[i] = (idx + i < m) ? src[idx + i] : 0;
        s += a[i];
    }
    sm[t] = s;
    __syncthreads();
    for (int off = 1; off < 256; off <<= 1) {
        int u = (t >= off) ? sm[t - off] : 0;
        __syncthreads();
        sm[t] += u;
        __syncthreads();
    }
    int run = sm[t] - s;                               // exclusive base
    int grand = sm[255];
#pragma unroll
    for (int i = 0; i < 4; ++i) {
        if (idx + i < m) dst[idx + i] = run;
        run += a[i];
    }
    if (t == 0) {
        if (grand_out) *grand_out = grand;
        if (write_end) dst[m] = grand;
    }
    __syncthreads();                                   // sm reuse safety
}

// ---- phase: scatter packed edges into bucket-grouped order ----------------

__device__ inline void scatter_body(const int* __restrict__ ei, int E, int nb,
                                    int chunk, const int* __restrict__ histT,
                                    const int* __restrict__ base,
                                    unsigned* __restrict__ packed, int vb,
                                    int* h) {
    const int t = threadIdx.x;
    for (int b = t; b < nb; b += 256)
        h[b] = base[b] + histT[(size_t)b * NVB + vb];
    __syncthreads();
    int e0 = vb * chunk, e1 = min(E, e0 + chunk);
    for (int e = e0 + t; e < e1; e += 256) {
        int s = ei[e], d = ei[E + e];
        int pos = atomicAdd(&h[d >> 6], 1);            // LDS atomic
        packed[pos] = (unsigned)s | ((unsigned)(d & 63) << 16);
    }
    __syncthreads();                                   // h reuse safety
}

// ---- phase: per-bucket padded CSR (pair-aligned, sentinel-padded) ---------

__device__ inline void csr_body(const unsigned* __restrict__ packed,
                                const int* __restrict__ base, int n, int b,
                                int* __restrict__ qbeg, int* __restrict__ qcnt,
                                float* __restrict__ dinv,
                                unsigned short* __restrict__ ssrcp,
                                unsigned short* __restrict__ hs1,
                                unsigned short* __restrict__ hs2,
                                int* cnt, int* cur) {
    const int t = threadIdx.x;
    const int p0 = base[b], p1 = base[b + 1];
    if (t < 64) cnt[t] = 0;
    __syncthreads();
    for (int p = p0 + t; p < p1; p += 256)
        atomicAdd(&cnt[(packed[p] >> 16) & 63], 1);
    __syncthreads();
    if (t < 64) {                      // wave 0: shuffle scan over padded degs
        int deg = cnt[t];
        int pdeg = (deg + 1) & ~1;
        int sum = pdeg;
#pragma unroll
        for (int d = 1; d < 64; d <<= 1) {
            int u = __shfl_up(sum, d, 64);
            if (t >= d) sum += u;
        }
        int excl = sum - pdeg;                         // even
        int pb = (2 + p0 + 128 * b + 1) & ~1;          // even bucket base
        int start = pb + excl;
        int node = (b << 6) + t;
        if (node < n) {
            qbeg[node] = start >> 1;                   // pair units
            qcnt[node] = pdeg >> 1;
            dinv[node] = 1.0f / sqrtf((float)(deg + 1));
        }
        cur[t] = start;
    }
    __syncthreads();
    for (int p = p0 + t; p < p1; p += 256) {
        unsigned k = packed[p];
        int pos = atomicAdd(&cur[(k >> 16) & 63], 1);
        ssrcp[pos] = (unsigned short)(k & 0xFFFFu);
    }
    __syncthreads();
    if (t < 64 && (cnt[t] & 1))
        ssrcp[cur[t]] = (unsigned short)n;             // sentinel pad
    if (b == 0) {                                      // zero row n + guard
        if (t < 64) {
            hs1[(size_t)n * 64 + t] = 0;
            hs2[(size_t)n * 64 + t] = 0;
        }
        if (t == 0) {
            ssrcp[0] = (unsigned short)n;
            ssrcp[1] = (unsigned short)n;
        }
    }
    __syncthreads();                                   // loop reuse safety
}

// ---- phase: GEMM 64x64 tile, HS = bf16(dinv * (X@W)) ----------------------

#define FMA4(A, s, wv)                                                         \
    (A).x += (s) * (wv).x; (A).y += (s) * (wv).y;                              \
    (A).z += (s) * (wv).z; (A).w += (s) * (wv).w;

template <int K>
__device__ inline void gemm_body(const float* __restrict__ X,
                                 const float* __restrict__ W,
                                 const float* __restrict__ dinv,
                                 unsigned short* __restrict__ HS, int n,
                                 int row0, float (*xl)[36], float (*wl)[64]) {
    const int t = threadIdx.x;
    const int tc = t & 15;
    const int tr = t >> 4;

    float4 acc[4];
    acc[0] = acc[1] = acc[2] = acc[3] = make_float4(0.f, 0.f, 0.f, 0.f);

    for (int k0 = 0; k0 < K; k0 += 32) {
#pragma unroll
        for (int i = 0; i < 2; ++i) {
            int idx = i * 256 + t;
            int r = idx >> 3, f4 = idx & 7;
            int gr = row0 + r;
            float4 v = make_float4(0.f, 0.f, 0.f, 0.f);
            if (gr < n) v = *(const float4*)(X + (size_t)gr * K + k0 + f4 * 4);
            *(float4*)&xl[r][f4 * 4] = v;
        }
#pragma unroll
        for (int i = 0; i < 2; ++i) {
            int idx = i * 256 + t;
            int kr = idx >> 4, f4 = idx & 15;
            *(float4*)&wl[kr][f4 * 4] =
                *(const float4*)(W + (size_t)(k0 + kr) * 64 + f4 * 4);
        }
        __syncthreads();

#pragma unroll
        for (int kk = 0; kk < 32; kk += 4) {
            float4 xv0 = *(float4*)&xl[tr * 4 + 0][kk];
            float4 xv1 = *(float4*)&xl[tr * 4 + 1][kk];
            float4 xv2 = *(float4*)&xl[tr * 4 + 2][kk];
            float4 xv3 = *(float4*)&xl[tr * 4 + 3][kk];
            float4 wv0 = *(float4*)&wl[kk + 0][tc * 4];
            float4 wv1 = *(float4*)&wl[kk + 1][tc * 4];
            float4 wv2 = *(float4*)&wl[kk + 2][tc * 4];
            float4 wv3 = *(float4*)&wl[kk + 3][tc * 4];

            FMA4(acc[0], xv0.x, wv0); FMA4(acc[0], xv0.y, wv1);
            FMA4(acc[0], xv0.z, wv2); FMA4(acc[0], xv0.w, wv3);
            FMA4(acc[1], xv1.x, wv0); FMA4(acc[1], xv1.y, wv1);
            FMA4(acc[1], xv1.z, wv2); FMA4(acc[1], xv1.w, wv3);
            FMA4(acc[2], xv2.x, wv0); FMA4(acc[2], xv2.y, wv1);
            FMA4(acc[2], xv2.z, wv2); FMA4(acc[2], xv2.w, wv3);
            FMA4(acc[3], xv3.x, wv0); FMA4(acc[3], xv3.y, wv1);
            FMA4(acc[3], xv3.z, wv2); FMA4(acc[3], xv3.w, wv3);
        }
        __syncthreads();
    }

#pragma unroll
    for (int ri = 0; ri < 4; ++ri) {
        int gr = row0 + tr * 4 + ri;
        if (gr < n) {
            float dv = dinv[gr];
            float4 o = acc[ri];
            ushort4 pk;
            pk.x = f2bf(o.x * dv); pk.y = f2bf(o.y * dv);
            pk.z = f2bf(o.z * dv); pk.w = f2bf(o.w * dv);
            *(ushort4*)(HS + (size_t)gr * 64 + tc * 4) = pk;
        }
    }
}

// ---- phase: aggregation, wave per node (proven R1 body) -------------------

__device__ inline void agg_body(const unsigned short* __restrict__ hs,
                                const int* __restrict__ qbeg,
                                const int* __restrict__ qcnt,
                                const unsigned short* __restrict__ ssrcp,
                                const float* __restrict__ dinv,
                                const float* __restrict__ bias,
                                float* __restrict__ out, int n, int vb,
                                bool relu) {
    int node = vb * 4 + ((int)threadIdx.x >> 6);
    if (node >= n) return;                 // no barriers below: safe skip
    node = __builtin_amdgcn_readfirstlane(node);
    const int lane = threadIdx.x & 63;
    const int c = lane & 7;                // channel octet: ch 8c..8c+7
    const int shH = (lane & 8) ? 16 : 0;   // pair half of edge g = lane>>3

    const uint4* hs4 = (const uint4*)hs;            // row = 8 uint4 (128 B)
    const unsigned* ssu = (const unsigned*)ssrcp;   // src pairs

    const int q0 = qbeg[node];
    const int m  = qcnt[node];

    const uint4 sv = hs4[(size_t)node * 8 + c];
    const float dv = dinv[node];
    const float4 bv0 = *(const float4*)(bias + 8 * c);
    const float4 bv1 = *(const float4*)(bias + 8 * c + 4);

    float ax[8];
#pragma unroll
    for (int k = 0; k < 8; ++k) ax[k] = 0.f;

    int qb = 0;
    for (; qb + 8 <= m; qb += 8) {                  // full batches: no selects
        unsigned ssl[8];
#pragma unroll
        for (int j = 0; j < 8; ++j) ssl[j] = ssu[q0 + qb + j];
        uint4 v[2];
#pragma unroll
        for (int i = 0; i < 2; ++i) {
            unsigned w = (lane & 32) ? ((lane & 16) ? ssl[4 * i + 3] : ssl[4 * i + 2])
                                     : ((lane & 16) ? ssl[4 * i + 1] : ssl[4 * i + 0]);
            int s = (int)((w >> shH) & 0xFFFFu);
            v[i] = hs4[(size_t)s * 8 + c];
        }
#pragma unroll
        for (int i = 0; i < 2; ++i) {
            ax[0] += blo(v[i].x); ax[1] += bhi(v[i].x);
            ax[2] += blo(v[i].y); ax[3] += bhi(v[i].y);
            ax[4] += blo(v[i].z); ax[5] += bhi(v[i].z);
            ax[6] += blo(v[i].w); ax[7] += bhi(v[i].w);
        }
    }
    const int rem = m - qb;
    if (rem) {                                      // one tail batch
        unsigned ssl[8];
#pragma unroll
        for (int j = 0; j < 8; ++j) {
            int q = (j < rem) ? (q0 + qb + j) : 0;  // 0 = {n,n} guard pair
            ssl[j] = ssu[q];
        }
        uint4 v[2];
#pragma unroll
        for (int i = 0; i < 2; ++i) {
            unsigned w = (lane & 32) ? ((lane & 16) ? ssl[4 * i + 3] : ssl[4 * i + 2])
                                     : ((lane & 16) ? ssl[4 * i + 1] : ssl[4 * i + 0]);
            int s = (int)((w >> shH) & 0xFFFFu);
            v[i] = hs4[(size_t)s * 8 + c];
        }
#pragma unroll
        for (int i = 0; i < 2; ++i) {
            ax[0] += blo(v[i].x); ax[1] += bhi(v[i].x);
            ax[2] += blo(v[i].y); ax[3] += bhi(v[i].y);
            ax[4] += blo(v[i].z); ax[5] += bhi(v[i].z);
            ax[6] += blo(v[i].w); ax[7] += bhi(v[i].w);
        }
    }

    // reduce over the 8 edge slots (lane bits 3..5); channels kept
#pragma unroll
    for (int k = 0; k < 8; ++k) {
        ax[k] += __shfl_xor(ax[k], 8, 64);
        ax[k] += __shfl_xor(ax[k], 16, 64);
        ax[k] += __shfl_xor(ax[k], 32, 64);
    }

    float r[8];
    r[0] = dv * (ax[0] + blo(sv.x)) + bv0.x;
    r[1] = dv * (ax[1] + bhi(sv.x)) + bv0.y;
    r[2] = dv * (ax[2] + blo(sv.y)) + bv0.z;
    r[3] = dv * (ax[3] + bhi(sv.y)) + bv0.w;
    r[4] = dv * (ax[4] + blo(sv.z)) + bv1.x;
    r[5] = dv * (ax[5] + bhi(sv.z)) + bv1.y;
    r[6] = dv * (ax[6] + blo(sv.w)) + bv1.z;
    r[7] = dv * (ax[7] + bhi(sv.w)) + bv1.w;
    if (relu) {
#pragma unroll
        for (int k = 0; k < 8; ++k) r[k] = fmaxf(r[k], 0.f);
    }
    if (lane < 16) {
        float4 o = (lane & 8) ? make_float4(r[4], r[5], r[6], r[7])
                              : make_float4(r[0], r[1], r[2], r[3]);
        *(float4*)(out + (size_t)node * 64 + 8 * c + 4 * ((lane >> 3) & 1)) = o;
    }
}

// ---- the fused cooperative kernel -----------------------------------------

__global__ __launch_bounds__(256, 4) void k_fused(GcnP P) {
    __shared__ int   h[NB_MAX];
    __shared__ int   sm[256];
    __shared__ int   cnt[64], cur[64];
    __shared__ float xl[64][36];
    __shared__ float wl[32][64];

    cg::grid_group grid = cg::this_grid();
    const int bx = blockIdx.x, gsz = gridDim.x;

    for (int vb = bx; vb < NVB; vb += gsz)
        hist_body(P.ei, P.E, P.nb, P.chunk, P.histT, vb, h);
    grid.sync();

    for (int b = bx; b < P.nb; b += gsz)
        scan_block(P.histT + (size_t)b * NVB, P.histT + (size_t)b * NVB,
                   NVB, &P.total[b], false, sm);
    grid.sync();

    if (bx == 0) scan_block(P.total, P.base, P.nb, nullptr, true, sm);
    grid.sync();

    for (int vb = bx; vb < NVB; vb += gsz)
        scatter_body(P.ei, P.E, P.nb, P.chunk, P.histT, P.base, P.packed, vb,
                     h);
    grid.sync();

    for (int b = bx; b < P.nb; b += gsz)
        csr_body(P.packed, P.base, P.n, b, P.qbeg, P.qcnt, P.dinv, P.ssrcp,
                 P.hs1, P.hs2, cnt, cur);
    grid.sync();

    const int nbG = (P.n + 63) >> 6;
    const int nbA = (P.n + 3) >> 2;

    for (int vb = bx; vb < nbG; vb += gsz)
        gemm_body<256>(P.x, P.W1, P.dinv, P.hs1, P.n, vb << 6, xl, wl);
    grid.sync();

    for (int vb = bx; vb < nbA; vb += gsz)
        agg_body(P.hs1, P.qbeg, P.qcnt, P.ssrcp, P.dinv, P.b1, P.hB, P.n, vb,
                 true);
    grid.sync();

    for (int vb = bx; vb < nbG; vb += gsz)
        gemm_body<64>(P.hB, P.W2, P.dinv, P.hs2, P.n, vb << 6, xl, wl);
    grid.sync();

    for (int vb = bx; vb < nbA; vb += gsz)
        agg_body(P.hs2, P.qbeg, P.qcnt, P.ssrcp, P.dinv, P.b2, P.out, P.n, vb,
                 false);
}

// ---- classic (non-cooperative) fallback wrappers --------------------------

__global__ __launch_bounds__(256) void c_hist(GcnP P) {
    __shared__ int h[NB_MAX];
    for (int vb = blockIdx.x; vb < NVB; vb += gridDim.x)
        hist_body(P.ei, P.E, P.nb, P.chunk, P.histT, vb, h);
}
__global__ __launch_bounds__(256) void c_scan_cols(GcnP P) {
    __shared__ int sm[256];
    int b = blockIdx.x;
    scan_block(P.histT + (size_t)b * NVB, P.histT + (size_t)b * NVB, NVB,
               &P.total[b], false, sm);
}
__global__ __launch_bounds__(256) void c_scan_tot(GcnP P) {
    __shared__ int sm[256];
    scan_block(P.total, P.base, P.nb, nullptr, true, sm);
}
__global__ __launch_bounds__(256) void c_scatter(GcnP P) {
    __shared__ int h[NB_MAX];
    for (int vb = blockIdx.x; vb < NVB; vb += gridDim.x)
        scatter_body(P.ei, P.E, P.nb, P.chunk, P.histT, P.base, P.packed, vb,
                     h);
}
__global__ __launch_bounds__(256) void c_csr(GcnP P) {
    __shared__ int cnt[64], cur[64];
    csr_body(P.packed, P.base, P.n, blockIdx.x, P.qbeg, P.qcnt, P.dinv,
             P.ssrcp, P.hs1, P.hs2, cnt, cur);
}
__global__ __launch_bounds__(256) void c_gemm1(GcnP P) {
    __shared__ float xl[64][36];
    __shared__ float wl[32][64];
    gemm_body<256>(P.x, P.W1, P.dinv, P.hs1, P.n, blockIdx.x << 6, xl, wl);
}
__global__ __launch_bounds__(256) void c_agg1(GcnP P) {
    agg_body(P.hs1, P.qbeg, P.qcnt, P.ssrcp, P.dinv, P.b1, P.hB, P.n,
             blockIdx.x, true);
}
__global__ __launch_bounds__(256) void c_gemm2(GcnP P) {
    __shared__ float xl[64][36];
    __shared__ float wl[32][64];
    gemm_body<64>(P.hB, P.W2, P.dinv, P.hs2, P.n, blockIdx.x << 6, xl, wl);
}
__global__ __launch_bounds__(256) void c_agg2(GcnP P) {
    agg_body(P.hs2, P.qbeg, P.qcnt, P.ssrcp, P.dinv, P.b2, P.out, P.n,
             blockIdx.x, false);
}

// ---- launch ----------------------------------------------------------------

extern "C" void kernel_launch(void* const* d_in, const int* in_sizes, int n_in,
                              void* d_out, int out_size, void* d_ws, size_t ws_size,
                              hipStream_t stream) {
    GcnP P;
    P.x  = (const float*)d_in[0];
    P.ei = (const int*)d_in[1];
    P.W1 = (const float*)d_in[2];
    P.b1 = (const float*)d_in[3];
    P.W2 = (const float*)d_in[4];
    P.b2 = (const float*)d_in[5];

    P.n = in_sizes[0] / 256;            // 50000 (< 65536: ushort src packing)
    P.E = in_sizes[1] / 2;              // 1600000
    P.nb = (P.n + 63) >> 6;             // 782 buckets
    P.chunk = (P.E + NVB - 1) / NVB;

    // workspace carve-up (256B aligned)
    char* ws = (char*)d_ws;
    auto carve = [&](size_t bytes) {
        void* p = (void*)ws;
        ws += (bytes + 255) & ~(size_t)255;
        return p;
    };
    P.histT  = (int*)carve((size_t)P.nb * NVB * 4);
    P.total  = (int*)carve((size_t)P.nb * 4);
    P.base   = (int*)carve((size_t)(P.nb + 1) * 4);
    P.packed = (unsigned*)carve((size_t)P.E * 4);
    P.ssrcp  = (unsigned short*)carve(((size_t)P.E + 128 * P.nb + 256) * 2);
    P.qbeg   = (int*)carve((size_t)P.n * 4);
    P.qcnt   = (int*)carve((size_t)P.n * 4);
    P.dinv   = (float*)carve((size_t)P.n * 4);
    P.hs1    = (unsigned short*)carve((size_t)(P.n + 1) * 64 * 2);
    P.hB     = (float*)carve((size_t)P.n * 64 * 4);
    P.hs2    = (unsigned short*)carve((size_t)(P.n + 1) * 64 * 2);
    P.out    = (float*)d_out;

    // occupancy pre-check (host-side query; capture-safe), cached
    static int coop_grid = -2;  // -2 = unknown, 0 = use classic, >0 = grid
    if (coop_grid == -2) {
        int maxb = 0, ncu = 0;
        hipError_t e1 = hipOccupancyMaxActiveBlocksPerMultiprocessor(
            &maxb, (const void*)k_fused, 256, 0);
        hipDeviceProp_t prop;
        hipError_t e2 = hipGetDeviceProperties(&prop, 0);
        ncu = prop.multiProcessorCount;
        if (e1 == hipSuccess && e2 == hipSuccess && maxb >= 1 && ncu >= 1) {
            long g = (long)maxb * ncu;
            coop_grid = (int)(g < NVB ? g : NVB);
        } else {
            coop_grid = 0;
        }
    }

    if (coop_grid > 0) {
        void* args[] = { &P };
        hipError_t err = hipLaunchCooperativeKernel(
            (void*)k_fused, dim3(coop_grid), dim3(256), args, 0, stream);
        if (err == hipSuccess) return;
        coop_grid = 0;   // never retry the coop path
    }

    // fallback: classic 9-dispatch pipeline (same bodies)
    const int nbG = (P.n + 63) >> 6;
    const int nbA = (P.n + 3) >> 2;
    c_hist<<<NVB, 256, 0, stream>>>(P);
    c_scan_cols<<<P.nb, 256, 0, stream>>>(P);
    c_scan_tot<<<1, 256, 0, stream>>>(P);
    c_scatter<<<NVB, 256, 0, stream>>>(P);
    c_csr<<<P.nb, 256, 0, stream>>>(P);
    c_gemm1<<<nbG, 256, 0, stream>>>(P);
    c_agg1<<<nbA, 256, 0, stream>>>(P);
    c_gemm2<<<nbG, 256, 0, stream>>>(P);
    c_agg2<<<nbA, 256, 0, stream>>>(P);
}

// Round 7
// 263.792 us; speedup vs baseline: 2.8210x; 2.8210x over previous
//
#include <hip/hip_runtime.h>
#include <hip/hip_bf16.h>

// GCN 2-layer: h1 = relu(Ahat @ (x@W1) + b1); out = Ahat @ (h1@W2) + b2
// Ahat = D^-1/2 (A + I) D^-1/2.
//
// Pipeline (zero global atomics on the edge path):
//   k_hist/k_scan/k_scatter: deterministic bucket partition (bucket=dst>>6)
//     via per-block LDS histograms. k_scan merges the per-bucket scan AND
//     the bucket-totals scan (last-block ticket pattern) -> one dispatch.
//   k_csr: per bucket -> per-node PAIR-ALIGNED, SENTINEL-PADDED src lists
//     (ssrcp; sentinel src = n -> zero row of hs), qbeg/qcnt, dinv; zeroes
//     hs row n and writes guard pair ssrcp[0..1] = {n,n}.
//   k_gemm: register-tiled 64x64; epilogue writes hs = bf16(dinv * (X@W)).
//   k_agg: wave per node; dual-edge dwordx4 gathers (8 edge-rows/instr),
//     8-pair batches, NO masks (sentinels add 0), scalar index loads; tail
//     batch pads via SALU cselect to the guard pair.
// LEDGER of tested theories (keep; prevents re-testing):
// R3:  never funnel E atomics into few global addresses.
// R5:  s_barrier is workgroup-scope; 64-wide scan in wave 0 uses shfl.
// R6:  bf16 rows halve gather bytes. R8: full-width batches beat scalar
//      remainder loops. R9: sentinel padding kills live-mask VALU.
// R10: prep kernels need 1024-thr blocks (4 waves/SIMD) - latency chains.
// R11: agg is NOT gather-instr bound (R1 A/B: 4x fewer VMEM = no change)
//      and NOT L3-capacity bound (R3 A/B: plane split = -37 us overhead).
// R13/R15: NOT dispatch-gap bound: full cooperative fusion = 744 us
//      (occupancy 24%, VALUBusy 6.6%, HBM 5%) - monolithic launch config
//      starves latency-sensitive phases of TLP; per-phase-tuned launches
//      are worth far more than the inter-dispatch gaps. Remaining levers
//      are INSIDE phases: agg random-line bytes, gemm256 VALU.
// R16 (this round): merge scan_cols+scan_totals via last-block ticket
//      (device-scope atomicAdd + threadfence + volatile re-read; ticket
//      zeroed in k_hist). 9 -> 8 dispatches, hot paths untouched.

#define NB_MAX 1024  // max buckets (n <= 65535 for ushort src packing)

__device__ inline unsigned short f2bf(float f) {      // RNE fp32 -> bf16
    unsigned u = __builtin_bit_cast(unsigned, f);
    return (unsigned short)((u + 0x7FFFu + ((u >> 16) & 1u)) >> 16);
}
__device__ inline float blo(unsigned u) {             // low bf16 -> fp32
    return __builtin_bit_cast(float, u << 16);
}
__device__ inline float bhi(unsigned u) {             // high bf16 -> fp32
    return __builtin_bit_cast(float, u & 0xFFFF0000u);
}

// ---- 1. per-block bucket histogram (256 blocks x 1024 thr = 4 waves/SIMD) -

__global__ __launch_bounds__(1024) void k_hist(const int* __restrict__ ei, int E,
                                               int nb, int chunk,
                                               int* __restrict__ histT,
                                               int* __restrict__ ticket) {
    __shared__ int h[NB_MAX];
    if (blockIdx.x == 0 && threadIdx.x == 0) *ticket = 0;  // for k_scan
    for (int i = threadIdx.x; i < nb; i += 1024) h[i] = 0;
    __syncthreads();
    int e0 = blockIdx.x * chunk, e1 = min(E, e0 + chunk);
    for (int e = e0 + threadIdx.x; e < e1; e += 1024)
        atomicAdd(&h[ei[E + e] >> 6], 1);          // LDS atomic
    __syncthreads();
    for (int b = threadIdx.x; b < nb; b += 1024)
        histT[b * 256 + blockIdx.x] = h[b];        // [bucket][block]
}

// ---- 2. scan each bucket's 256 per-block counts; last block also scans ----
//         the nb bucket totals into base[] (exclusive, base[nb] = E).

__global__ __launch_bounds__(256) void k_scan(int* __restrict__ histT,
                                              int* __restrict__ total,
                                              int* __restrict__ base, int nb,
                                              int* __restrict__ ticket) {
    __shared__ int sm[256];
    __shared__ int lastflag;
    const int b = blockIdx.x, t = threadIdx.x;
    int v = histT[b * 256 + t];
    sm[t] = v;
    __syncthreads();
    for (int off = 1; off < 256; off <<= 1) {
        int u = (t >= off) ? sm[t - off] : 0;
        __syncthreads();
        sm[t] += u;
        __syncthreads();
    }
    histT[b * 256 + t] = sm[t] - v;                // exclusive within bucket
    if (t == 255) total[b] = sm[255];

    // last-arriving block scans the totals (release: fence before ticket)
    __threadfence();
    __syncthreads();
    if (t == 0) lastflag = (atomicAdd(ticket, 1) == nb - 1) ? 1 : 0;
    __syncthreads();
    if (!lastflag) return;
    __threadfence();                               // acquire
    const volatile int* vt = (const volatile int*)total;
    const int idx = t * 4;
    int a[4]; int s = 0;
#pragma unroll
    for (int i = 0; i < 4; ++i) {
        a[i] = (idx + i < nb) ? vt[idx + i] : 0;
        s += a[i];
    }
    __syncthreads();                               // sm reuse
    sm[t] = s;
    __syncthreads();
    for (int off = 1; off < 256; off <<= 1) {
        int u = (t >= off) ? sm[t - off] : 0;
        __syncthreads();
        sm[t] += u;
        __syncthreads();
    }
    int run = sm[t] - s;
    int grand = sm[255];
#pragma unroll
    for (int i = 0; i < 4; ++i) {
        if (idx + i < nb) base[idx + i] = run;
        run += a[i];
    }
    if (t == 0) base[nb] = grand;                  // total E
}

// ---- 3. scatter packed edges into bucket-grouped order --------------------

__global__ __launch_bounds__(1024) void k_scatter(const int* __restrict__ ei, int E,
                                                  int nb, int chunk,
                                                  const int* __restrict__ histT,
                                                  const int* __restrict__ base,
                                                  unsigned* __restrict__ packed) {
    __shared__ int cur[NB_MAX];
    for (int b = threadIdx.x; b < nb; b += 1024)
        cur[b] = base[b] + histT[b * 256 + blockIdx.x];
    __syncthreads();
    int e0 = blockIdx.x * chunk, e1 = min(E, e0 + chunk);
    for (int e = e0 + threadIdx.x; e < e1; e += 1024) {
        int s = ei[e], d = ei[E + e];
        int pos = atomicAdd(&cur[d >> 6], 1);      // LDS atomic
        packed[pos] = (unsigned)s | ((unsigned)(d & 63) << 16);
    }
}

// ---- 4. per-bucket padded CSR: qbeg/qcnt (pair units), dinv, ssrcp --------
// Each node's list starts at an even ushort index and is padded to even
// length with sentinel src = n (zero hs row). Bucket b's region starts at
// pb = even(2 + base[b] + 128*b): 128-slot slack > max 64 pads per bucket.

__global__ __launch_bounds__(1024) void k_csr(const unsigned* __restrict__ packed,
                                              const int* __restrict__ base,
                                              int n,
                                              int* __restrict__ qbeg,
                                              int* __restrict__ qcnt,
                                              float* __restrict__ dinv,
                                              unsigned short* __restrict__ ssrcp,
                                              unsigned short* __restrict__ hs1,
                                              unsigned short* __restrict__ hs2) {
    __shared__ int cnt[64];
    __shared__ int cur[64];
    const int b = blockIdx.x, t = threadIdx.x;
    const int p0 = base[b], p1 = base[b + 1];
    if (t < 64) cnt[t] = 0;
    __syncthreads();
    for (int p = p0 + t; p < p1; p += 1024)
        atomicAdd(&cnt[(packed[p] >> 16) & 63], 1);
    __syncthreads();
    if (t < 64) {                      // wave 0: shuffle scan over padded degs
        int deg = cnt[t];
        int pdeg = (deg + 1) & ~1;     // even-padded degree
        int sum = pdeg;
#pragma unroll
        for (int d = 1; d < 64; d <<= 1) {
            int u = __shfl_up(sum, d, 64);
            if (t >= d) sum += u;
        }
        int excl = sum - pdeg;                       // even
        int pb = (2 + p0 + 128 * b + 1) & ~1;        // even bucket base
        int start = pb + excl;                       // even
        int node = (b << 6) + t;
        if (node < n) {
            qbeg[node] = start >> 1;                 // pair units (>= 1)
            qcnt[node] = pdeg >> 1;
            dinv[node] = 1.0f / sqrtf((float)(deg + 1));  // +1 self-loop
        }
        cur[t] = start;
    }
    __syncthreads();
    for (int p = p0 + t; p < p1; p += 1024) {
        unsigned k = packed[p];
        int pos = atomicAdd(&cur[(k >> 16) & 63], 1);
        ssrcp[pos] = (unsigned short)(k & 0xFFFFu);  // ~4 KB window scatter
    }
    __syncthreads();
    if (t < 64 && (cnt[t] & 1))                      // sentinel pad to even
        ssrcp[cur[t]] = (unsigned short)n;
    if (b == 0) {                                    // zero row n + guard pair
        if (t < 64) {
            hs1[(size_t)n * 64 + t] = 0;
            hs2[(size_t)n * 64 + t] = 0;
        }
        if (t == 0) {
            ssrcp[0] = (unsigned short)n;
            ssrcp[1] = (unsigned short)n;
        }
    }
}

// ---- GEMM: HS[n,64] = bf16( dinv[:,None] * (X[n,K] @ W[K,64]) ) ------------
// Register-tiled: block(256) = 64x64 tile; thread = 4x4. dinv pre-scale fused.

#define FMA4(A, s, wv)                                                         \
    (A).x += (s) * (wv).x; (A).y += (s) * (wv).y;                              \
    (A).z += (s) * (wv).z; (A).w += (s) * (wv).w;

template <int K>
__global__ __launch_bounds__(256) void k_gemm(const float* __restrict__ X,
                                              const float* __restrict__ W,
                                              const float* __restrict__ dinv,
                                              unsigned short* __restrict__ HS,
                                              int n) {
    __shared__ float xl[64][36];
    __shared__ float wl[32][64];

    const int t = threadIdx.x;
    const int tc = t & 15;
    const int tr = t >> 4;
    const int row0 = blockIdx.x * 64;

    float4 acc[4];
    acc[0] = acc[1] = acc[2] = acc[3] = make_float4(0.f, 0.f, 0.f, 0.f);

    for (int k0 = 0; k0 < K; k0 += 32) {
#pragma unroll
        for (int i = 0; i < 2; ++i) {
            int idx = i * 256 + t;
            int r = idx >> 3, f4 = idx & 7;
            int gr = row0 + r;
            float4 v = make_float4(0.f, 0.f, 0.f, 0.f);
            if (gr < n) v = *(const float4*)(X + (size_t)gr * K + k0 + f4 * 4);
            *(float4*)&xl[r][f4 * 4] = v;
        }
#pragma unroll
        for (int i = 0; i < 2; ++i) {
            int idx = i * 256 + t;
            int kr = idx >> 4, f4 = idx & 15;
            *(float4*)&wl[kr][f4 * 4] =
                *(const float4*)(W + (size_t)(k0 + kr) * 64 + f4 * 4);
        }
        __syncthreads();

#pragma unroll
        for (int kk = 0; kk < 32; kk += 4) {
            float4 xv0 = *(float4*)&xl[tr * 4 + 0][kk];
            float4 xv1 = *(float4*)&xl[tr * 4 + 1][kk];
            float4 xv2 = *(float4*)&xl[tr * 4 + 2][kk];
            float4 xv3 = *(float4*)&xl[tr * 4 + 3][kk];
            float4 wv0 = *(float4*)&wl[kk + 0][tc * 4];
            float4 wv1 = *(float4*)&wl[kk + 1][tc * 4];
            float4 wv2 = *(float4*)&wl[kk + 2][tc * 4];
            float4 wv3 = *(float4*)&wl[kk + 3][tc * 4];

            FMA4(acc[0], xv0.x, wv0); FMA4(acc[0], xv0.y, wv1);
            FMA4(acc[0], xv0.z, wv2); FMA4(acc[0], xv0.w, wv3);
            FMA4(acc[1], xv1.x, wv0); FMA4(acc[1], xv1.y, wv1);
            FMA4(acc[1], xv1.z, wv2); FMA4(acc[1], xv1.w, wv3);
            FMA4(acc[2], xv2.x, wv0); FMA4(acc[2], xv2.y, wv1);
            FMA4(acc[2], xv2.z, wv2); FMA4(acc[2], xv2.w, wv3);
            FMA4(acc[3], xv3.x, wv0); FMA4(acc[3], xv3.y, wv1);
            FMA4(acc[3], xv3.z, wv2); FMA4(acc[3], xv3.w, wv3);
        }
        __syncthreads();
    }

#pragma unroll
    for (int ri = 0; ri < 4; ++ri) {
        int gr = row0 + tr * 4 + ri;
        if (gr < n) {
            float dv = dinv[gr];
            float4 o = acc[ri];
            ushort4 pk;
            pk.x = f2bf(o.x * dv); pk.y = f2bf(o.y * dv);
            pk.z = f2bf(o.z * dv); pk.w = f2bf(o.w * dv);
            *(ushort4*)(HS + (size_t)gr * 64 + tc * 4) = pk;
        }
    }
}

// ---- 5. aggregation: out[i] = dinv[i]*(sum_src hs[src] + hs[i]) + b -------
// Wave per node. dwordx4 gathers: one instr = 64 lanes x 16B = 8 edge-rows
// (lane -> edge g = lane>>3, channel octet c = lane&7). 8-pair batches,
// all pairs live (sentinel padding) so NO masks; full batches use
// consecutive scalar index loads (s_load_dwordx8); tail batch selects dead
// slots to guard pair 0 via SALU cselect. 3-level xor-shuffle edge reduce.

template <bool RELU>
__global__ __launch_bounds__(256) void k_agg(const unsigned short* __restrict__ hs,  // n+1 rows
                      const int* __restrict__ qbeg,
                      const int* __restrict__ qcnt,
                      const unsigned short* __restrict__ ssrcp,
                      const float* __restrict__ dinv,
                      const float* __restrict__ bias,
                      float* __restrict__ out, int n) {
    int node = blockIdx.x * 4 + (threadIdx.x >> 6);
    if (node >= n) return;
    node = __builtin_amdgcn_readfirstlane(node);   // SGPR -> scalar loads
    const int lane = threadIdx.x & 63;
    const int c = lane & 7;               // channel octet: ch 8c..8c+7
    const int shH = (lane & 8) ? 16 : 0;  // pair half of edge g = lane>>3

    const uint4* hs4 = (const uint4*)hs;           // row = 8 uint4 (128 B)
    const unsigned* ssu = (const unsigned*)ssrcp;  // src pairs

    const int q0 = qbeg[node];
    const int m  = qcnt[node];

    // epilogue operands issued early, in flight during the gather loop
    const uint4 sv = hs4[(size_t)node * 8 + c];
    const float dv = dinv[node];
    const float4 bv0 = *(const float4*)(bias + 8 * c);
    const float4 bv1 = *(const float4*)(bias + 8 * c + 4);

    float ax[8];
#pragma unroll
    for (int k = 0; k < 8; ++k) ax[k] = 0.f;

    int qb = 0;
    for (; qb + 8 <= m; qb += 8) {                 // full batches: no selects
        unsigned ssl[8];
#pragma unroll
        for (int j = 0; j < 8; ++j) ssl[j] = ssu[q0 + qb + j];
        uint4 v[2];
#pragma unroll
        for (int i = 0; i < 2; ++i) {              // instr i covers pairs 4i..4i+3
            unsigned w = (lane & 32) ? ((lane & 16) ? ssl[4 * i + 3] : ssl[4 * i + 2])
                                     : ((lane & 16) ? ssl[4 * i + 1] : ssl[4 * i + 0]);
            int s = (int)((w >> shH) & 0xFFFFu);
            v[i] = hs4[(size_t)s * 8 + c];
        }
#pragma unroll
        for (int i = 0; i < 2; ++i) {
            ax[0] += blo(v[i].x); ax[1] += bhi(v[i].x);
            ax[2] += blo(v[i].y); ax[3] += bhi(v[i].y);
            ax[4] += blo(v[i].z); ax[5] += bhi(v[i].z);
            ax[6] += blo(v[i].w); ax[7] += bhi(v[i].w);
        }
    }
    const int rem = m - qb;
    if (rem) {                                     // one tail batch, SALU sel
        unsigned ssl[8];
#pragma unroll
        for (int j = 0; j < 8; ++j) {
            int q = (j < rem) ? (q0 + qb + j) : 0; // 0 = {n,n} guard pair
            ssl[j] = ssu[q];
        }
        uint4 v[2];
#pragma unroll
        for (int i = 0; i < 2; ++i) {
            unsigned w = (lane & 32) ? ((lane & 16) ? ssl[4 * i + 3] : ssl[4 * i + 2])
                                     : ((lane & 16) ? ssl[4 * i + 1] : ssl[4 * i + 0]);
            int s = (int)((w >> shH) & 0xFFFFu);
            v[i] = hs4[(size_t)s * 8 + c];
        }
#pragma unroll
        for (int i = 0; i < 2; ++i) {
            ax[0] += blo(v[i].x); ax[1] += bhi(v[i].x);
            ax[2] += blo(v[i].y); ax[3] += bhi(v[i].y);
            ax[4] += blo(v[i].z); ax[5] += bhi(v[i].z);
            ax[6] += blo(v[i].w); ax[7] += bhi(v[i].w);
        }
    }

    // reduce over the 8 edge slots (lane bits 3..5); channels (bits 0..2) kept
#pragma unroll
    for (int k = 0; k < 8; ++k) {
        ax[k] += __shfl_xor(ax[k], 8, 64);
        ax[k] += __shfl_xor(ax[k], 16, 64);
        ax[k] += __shfl_xor(ax[k], 32, 64);
    }

    // epilogue: self-loop + scale + bias (+ relu); lanes 0..15 store 256 B
    float r[8];
    r[0] = dv * (ax[0] + blo(sv.x)) + bv0.x;
    r[1] = dv * (ax[1] + bhi(sv.x)) + bv0.y;
    r[2] = dv * (ax[2] + blo(sv.y)) + bv0.z;
    r[3] = dv * (ax[3] + bhi(sv.y)) + bv0.w;
    r[4] = dv * (ax[4] + blo(sv.z)) + bv1.x;
    r[5] = dv * (ax[5] + bhi(sv.z)) + bv1.y;
    r[6] = dv * (ax[6] + blo(sv.w)) + bv1.z;
    r[7] = dv * (ax[7] + bhi(sv.w)) + bv1.w;
    if (RELU) {
#pragma unroll
        for (int k = 0; k < 8; ++k) r[k] = fmaxf(r[k], 0.f);
    }
    if (lane < 16) {
        float4 o = (lane & 8) ? make_float4(r[4], r[5], r[6], r[7])
                              : make_float4(r[0], r[1], r[2], r[3]);
        *(float4*)(out + (size_t)node * 64 + 8 * c + 4 * ((lane >> 3) & 1)) = o;
    }
}

// ---- launch ----------------------------------------------------------------

extern "C" void kernel_launch(void* const* d_in, const int* in_sizes, int n_in,
                              void* d_out, int out_size, void* d_ws, size_t ws_size,
                              hipStream_t stream) {
    const float* x  = (const float*)d_in[0];
    const int*   ei = (const int*)d_in[1];
    const float* W1 = (const float*)d_in[2];
    const float* b1 = (const float*)d_in[3];
    const float* W2 = (const float*)d_in[4];
    const float* b2 = (const float*)d_in[5];

    const int n = in_sizes[0] / 256;   // 50000 (< 65536: ushort src packing)
    const int E = in_sizes[1] / 2;     // 1600000
    const int nb = (n + 63) >> 6;      // 782 buckets
    const int chunk = (E + 255) / 256;

    // workspace carve-up (256B aligned)
    char* ws = (char*)d_ws;
    auto carve = [&](size_t bytes) {
        void* p = (void*)ws;
        ws += (bytes + 255) & ~(size_t)255;
        return p;
    };
    int*            histT  = (int*)carve((size_t)nb * 256 * 4);
    int*            total  = (int*)carve((size_t)nb * 4);
    int*            base   = (int*)carve((size_t)(nb + 1) * 4);
    int*            ticket = (int*)carve(256);
    unsigned*       packed = (unsigned*)carve((size_t)E * 4);
    unsigned short* ssrcp  = (unsigned short*)carve(((size_t)E + 128 * nb + 256) * 2);
    int*            qbeg   = (int*)carve((size_t)n * 4);
    int*            qcnt   = (int*)carve((size_t)n * 4);
    float*          dinv   = (float*)carve((size_t)n * 4);
    unsigned short* hs1    = (unsigned short*)carve((size_t)(n + 1) * 64 * 2);
    float*          hB     = (float*)carve((size_t)n * 64 * 4);
    unsigned short* hs2    = (unsigned short*)carve((size_t)(n + 1) * 64 * 2);

    k_hist<<<256, 1024, 0, stream>>>(ei, E, nb, chunk, histT, ticket);
    k_scan<<<nb, 256, 0, stream>>>(histT, total, base, nb, ticket);
    k_scatter<<<256, 1024, 0, stream>>>(ei, E, nb, chunk, histT, base, packed);
    k_csr<<<nb, 1024, 0, stream>>>(packed, base, n, qbeg, qcnt, dinv, ssrcp,
                                   hs1, hs2);

    const int nbG = (n + 63) / 64;
    const int nbA = (n + 3) / 4;

    // layer 1: hs1 = bf16(dinv*(x@W1)) ; hB = relu(agg + b1)
    k_gemm<256><<<nbG, 256, 0, stream>>>(x, W1, dinv, hs1, n);
    k_agg<true><<<nbA, 256, 0, stream>>>(hs1, qbeg, qcnt, ssrcp, dinv,
                                         b1, hB, n);

    // layer 2: hs2 = bf16(dinv*(hB@W2)) ; out = agg + b2
    k_gemm<64><<<nbG, 256, 0, stream>>>(hB, W2, dinv, hs2, n);
    k_agg<false><<<nbA, 256, 0, stream>>>(hs2, qbeg, qcnt, ssrcp, dinv,
                                          b2, (float*)d_out, n);
}